// Round 14
// baseline (349.006 us; speedup 1.0000x reference)
//
#include <hip/hip_runtime.h>
#include <hip/hip_bf16.h>
#include <hip/hip_fp16.h>
#include <math.h>

typedef unsigned short u16;
typedef unsigned int u32;
typedef __attribute__((ext_vector_type(8))) short bf16x8;
typedef __attribute__((ext_vector_type(4))) float f32x4;

#define N_NODES 8192
#define DIM 512
#define KSEL 31
#define BANDCAP 64
#define SEG_SIZE 2048
#define NVALID 6144   // cross-segment columns per row
#define BAND_ULP 8    // band half-width in f16 ulps (covers 2E, E<=4 ulps)

__device__ __forceinline__ float ninf() { return __int_as_float(0xff800000); }

// monotone 16-bit key from f16 bits (larger key <=> larger value)
__device__ __forceinline__ u32 f16key(u32 h) {
  return (h & 0x8000u) ? (0xFFFFu & ~h) : (h | 0x8000u);
}
__device__ __forceinline__ float keyval(u32 k) {
  const u16 raw = (k & 0x8000u) ? (u16)(k ^ 0x8000u) : (u16)(~k & 0xFFFFu);
  __half_raw hr; hr.x = raw;
  return __half2float(__half(hr));
}

#define GLD_LDS16(g, l)                                        \
  __builtin_amdgcn_global_load_lds(                            \
      (const __attribute__((address_space(1))) void*)(g),      \
      (__attribute__((address_space(3))) void*)(l), 16, 0, 0)

// ---------------------------------------------------------------------------
// Kernel 1: emb replicating numpy-f32 bit-exactly (verified R6).
// ---------------------------------------------------------------------------
__global__ __launch_bounds__(256) void prep_kernel(
    const float* __restrict__ feat, const float* __restrict__ w0,
    const float* __restrict__ w1, u16* __restrict__ embh,
    float* __restrict__ embf) {
#pragma clang fp contract(off)
  const int row = blockIdx.x;
  const int t = threadIdx.x;
  __shared__ float hs[DIM];
  __shared__ float partial[32];
  __shared__ float rinv_sh;

  const float2 x = *reinterpret_cast<const float2*>(feat + (size_t)row * DIM + t * 2);
  const float2 a = *reinterpret_cast<const float2*>(w0 + t * 2);
  const float2 b = *reinterpret_cast<const float2*>(w1 + t * 2);
  const float h0 = fmaxf(x.x * a.x, 0.0f) * b.x;
  const float h1 = fmaxf(x.y * a.y, 0.0f) * b.y;
  hs[t * 2] = h0;
  hs[t * 2 + 1] = h1;
  __syncthreads();

  if (t < 32) {
    const int base = (t >> 3) * 128 + (t & 7);
    float v = hs[base];
    float acc = v * v;
    for (int i = 1; i < 16; ++i) {
      v = hs[base + 8 * i];
      const float vv = v * v;
      acc = acc + vv;
    }
    partial[t] = acc;
  }
  __syncthreads();
  if (t == 0) {
    float B[4];
    for (int blk = 0; blk < 4; ++blk) {
      const float* p = &partial[blk * 8];
      B[blk] = ((p[0] + p[1]) + (p[2] + p[3])) + ((p[4] + p[5]) + (p[6] + p[7]));
    }
    const float s = (B[0] + B[1]) + (B[2] + B[3]);
    const float sp = s + 1e-24f;
    const float qf = (float)sqrt((double)sp);
    rinv_sh = (float)(1.0 / (double)qf);
  }
  __syncthreads();
  const float rinv = rinv_sh;
  const float e0 = h0 * rinv;
  const float e1 = h1 * rinv;
  *reinterpret_cast<float2*>(embf + (size_t)row * DIM + t * 2) = make_float2(e0, e1);
  __hip_bfloat162 bb;
  bb.x = __float2bfloat16(e0);
  bb.y = __float2bfloat16(e1);
  *reinterpret_cast<__hip_bfloat162*>(embh + (size_t)row * DIM + t * 2) = bb;
}

// ---------------------------------------------------------------------------
// Kernel 2: ranking sim (bf16 MFMA) -> f16, packed cross-seg columns.
// ---------------------------------------------------------------------------
__global__ __launch_bounds__(256) void gemm_kernel(const u16* __restrict__ embh,
                                                   __half* __restrict__ simh) {
  __shared__ u16 As[128][64];
  __shared__ u16 Bs[128][64];
  const int tid = threadIdx.x;
  const int lane = tid & 63;
  const int wave = tid >> 6;
  const int wm = wave >> 1;
  const int wn = wave & 1;
  const int rowTile = blockIdx.y;
  const int segTileBase = (rowTile >> 4) << 4;
  const int cT = blockIdx.x;
  const int colTile = cT < segTileBase ? cT : cT + 16;
  const int row0 = rowTile * 128;
  const int col0 = colTile * 128;

  f32x4 acc[4][4] = {};

  for (int k0 = 0; k0 < DIM; k0 += 64) {
#pragma unroll
    for (int i = 0; i < 4; ++i) {
      const int flat = i * 256 + tid;
      const int r = flat >> 3;
      const int c = (flat & 7) * 8;
      GLD_LDS16(embh + (size_t)(row0 + r) * DIM + k0 + c, &As[r][c]);
      GLD_LDS16(embh + (size_t)(col0 + r) * DIM + k0 + c, &Bs[r][c]);
    }
    __syncthreads();
#pragma unroll
    for (int kk = 0; kk < 2; ++kk) {
      bf16x8 afr[4], bfr[4];
      const int koff = kk * 32 + (lane >> 4) * 8;
      const int rsel = lane & 15;
#pragma unroll
      for (int m = 0; m < 4; ++m)
        afr[m] = *reinterpret_cast<const bf16x8*>(&As[wm * 64 + m * 16 + rsel][koff]);
#pragma unroll
      for (int n = 0; n < 4; ++n)
        bfr[n] = *reinterpret_cast<const bf16x8*>(&Bs[wn * 64 + n * 16 + rsel][koff]);
#pragma unroll
      for (int m = 0; m < 4; ++m)
#pragma unroll
        for (int n = 0; n < 4; ++n)
          acc[m][n] = __builtin_amdgcn_mfma_f32_16x16x32_bf16(afr[m], bfr[n],
                                                              acc[m][n], 0, 0, 0);
    }
    __syncthreads();
  }
#pragma unroll
  for (int m = 0; m < 4; ++m)
#pragma unroll
    for (int n = 0; n < 4; ++n)
#pragma unroll
      for (int j = 0; j < 4; ++j) {
        const int r = row0 + wm * 64 + m * 16 + (lane >> 4) * 4 + j;
        const int pcol = cT * 128 + wn * 64 + n * 16 + (lane & 15);
        simh[(size_t)r * NVALID + pcol] = __float2half(acc[m][n][j]);
      }
}

// ---------------------------------------------------------------------------
// Kernel 3: per-row selection, register-resident row. 2-pass radix for the
// 31st f16 key; H = {key > key31+8ulp} certainly-in (value = f16);
// band [key31-8, key31+8] resolved by bit-exact np-sequential dots (~9/row).
// ---------------------------------------------------------------------------
__global__ __launch_bounds__(256) void select_kernel(
    const __half* __restrict__ simh, const float* __restrict__ embf,
    int2* __restrict__ compact) {
  const int row = blockIdx.x;
  const int t = threadIdx.x;
  const int lane = t & 63;
  const int wave = t >> 6;

  __shared__ __align__(16) float er[DIM];
  __shared__ u32 hist[2][4][257];
  __shared__ u32 above_s, prefix_s;
  __shared__ int nH_s, nB_s, outcnt_s;
  __shared__ int bcol[BANDCAP];
  __shared__ float bex[BANDCAP];
  __shared__ int outidx[KSEL];
  __shared__ float outval[KSEL];

  const int segBase = (row >> 11) << 11;

  // load row into registers: 3 coalesced uint4 per thread (24 f16 values)
  uint4 q0, q1, q2;
  {
    const uint4* src = reinterpret_cast<const uint4*>(simh + (size_t)row * NVALID);
    q0 = src[t];
    q1 = src[256 + t];
    q2 = src[512 + t];
  }
  if (t < 128)
    reinterpret_cast<float4*>(er)[t] =
        reinterpret_cast<const float4*>(embf + (size_t)row * DIM)[t];
  {
    u32* hf = &hist[0][0][0];
    for (int z = t; z < 2 * 4 * 257; z += 256) hf[z] = 0;
  }
  if (t < KSEL) { outidx[t] = segBase; outval[t] = 0.0f; }
  if (t == 0) { above_s = 0; prefix_s = 0; nH_s = 0; nB_s = 0; outcnt_s = 0; }
  __syncthreads();

  // extract the 24 keys once (static unroll -> stays in VGPRs)
  u32 key[24];
#pragma unroll
  for (int r = 0; r < 3; ++r) {
    const uint4 q = (r == 0) ? q0 : (r == 1) ? q1 : q2;
    const u32 w[4] = {q.x, q.y, q.z, q.w};
#pragma unroll
    for (int e = 0; e < 8; ++e)
      key[r * 8 + e] = f16key((w[e >> 1] >> (16 * (e & 1))) & 0xFFFFu);
  }

  // pass 0: upper-byte histogram, ballot-aggregated (keys are clustered)
#pragma unroll
  for (int v = 0; v < 24; ++v) {
    const u32 bin = key[v] >> 8;
    unsigned long long act = __ballot(1);
    while (act) {
      const int leader = (int)(__ffsll((unsigned long long)act) - 1);
      const u32 lb = __shfl(bin, leader, 64);
      const unsigned long long eq = __ballot(bin == lb) & act;
      if (lane == leader)
        atomicAdd(&hist[0][wave][lb], (u32)__popcll(eq));
      act &= ~eq;
    }
  }
  __syncthreads();
  // reduce pass 0 (select bin containing the 31st largest)
  if (wave == 0) {
    const int x = lane * 4;
    u32 b0 = 0, b1 = 0, b2 = 0, b3 = 0;
#pragma unroll
    for (int z = 0; z < 4; ++z) {
      b0 += hist[0][z][x]; b1 += hist[0][z][x + 1];
      b2 += hist[0][z][x + 2]; b3 += hist[0][z][x + 3];
    }
    const u32 tot = b0 + b1 + b2 + b3;
    u32 inc = tot;
#pragma unroll
    for (int off = 1; off < 64; off <<= 1) {
      const u32 v = __shfl_down(inc, off, 64);
      if (lane + off < 64) inc += v;
    }
    const u32 exc = inc - tot;
    const u32 need = KSEL;
    const u32 g3 = exc;
    const u32 g2 = g3 + b3;
    const u32 g1 = g2 + b2;
    const u32 g0 = g1 + b1;
    int sel = -1;
    u32 gsel = 0;
    if (g3 < need && g3 + b3 >= need) { sel = x + 3; gsel = g3; }
    else if (g2 < need && g2 + b2 >= need) { sel = x + 2; gsel = g2; }
    else if (g1 < need && g1 + b1 >= need) { sel = x + 1; gsel = g1; }
    else if (g0 < need && g0 + b0 >= need) { sel = x;     gsel = g0; }
    if (sel >= 0) { prefix_s = (u32)sel; above_s = gsel; }
  }
  __syncthreads();

  // pass 1: lower-byte histogram among prefix-matching keys (from regs)
  {
    const u32 pref = prefix_s;
#pragma unroll
    for (int v = 0; v < 24; ++v)
      if ((key[v] >> 8) == pref) atomicAdd(&hist[1][wave][key[v] & 0xFFu], 1u);
  }
  __syncthreads();
  // reduce pass 1 -> full 16-bit 31st key
  if (wave == 0) {
    const int x = lane * 4;
    u32 b0 = 0, b1 = 0, b2 = 0, b3 = 0;
#pragma unroll
    for (int z = 0; z < 4; ++z) {
      b0 += hist[1][z][x]; b1 += hist[1][z][x + 1];
      b2 += hist[1][z][x + 2]; b3 += hist[1][z][x + 3];
    }
    const u32 tot = b0 + b1 + b2 + b3;
    u32 inc = tot;
#pragma unroll
    for (int off = 1; off < 64; off <<= 1) {
      const u32 v = __shfl_down(inc, off, 64);
      if (lane + off < 64) inc += v;
    }
    const u32 exc = inc - tot;
    const u32 need = KSEL - above_s;
    const u32 g3 = exc;
    const u32 g2 = g3 + b3;
    const u32 g1 = g2 + b2;
    const u32 g0 = g1 + b1;
    int sel = -1;
    if (g3 < need && g3 + b3 >= need) sel = x + 3;
    else if (g2 < need && g2 + b2 >= need) sel = x + 2;
    else if (g1 < need && g1 + b1 >= need) sel = x + 1;
    else if (g0 < need && g0 + b0 >= need) sel = x;
    if (sel >= 0) prefix_s = (prefix_s << 8) | (u32)sel;
  }
  __syncthreads();

  const u32 k31 = prefix_s;
  const u32 hiK = k31 + BAND_ULP;                       // H: key > hiK
  const u32 loK = (k31 >= BAND_ULP) ? k31 - BAND_ULP : 0;

  // classify from regs: count H, collect band members
  {
    int myH = 0;
#pragma unroll
    for (int r = 0; r < 3; ++r) {
#pragma unroll
      for (int e = 0; e < 8; ++e) {
        const u32 kk = key[r * 8 + e];
        if (kk > hiK) {
          myH++;
        } else if (kk >= loK) {
          const int slot = atomicAdd(&nB_s, 1);
          if (slot < BANDCAP) {
            const int i = (r * 256 + t) * 8 + e;  // packed col
            bcol[slot] = (i < segBase ? i : i + SEG_SIZE);
          }
        }
      }
    }
#pragma unroll
    for (int o = 32; o > 0; o >>= 1) myH += __shfl_down(myH, o, 64);
    if (lane == 0) atomicAdd(&nH_s, myH);
  }
  __syncthreads();
  const int nH = nH_s;
  const int nB = min(nB_s, BANDCAP);
  const int slots = KSEL - nH;

  // bit-exact np-sequential dots for band members (verified R6 rounding)
  if (t < nB) {
#pragma clang fp contract(off)
    const float4* g4 = reinterpret_cast<const float4*>(embf + (size_t)bcol[t] * DIM);
    const float4* e4 = reinterpret_cast<const float4*>(er);
    float acc = 0.0f;
    for (int k4 = 0; k4 < DIM / 4; ++k4) {
      const float4 a = e4[k4];
      const float4 b = g4[k4];
      acc = acc + a.x * b.x;
      acc = acc + a.y * b.y;
      acc = acc + a.z * b.z;
      acc = acc + a.w * b.w;
    }
    bex[t] = acc;
  }
  __syncthreads();

  // rank band by (exact desc, col asc); keep top-`slots`
  if (wave == 0 && lane < nB) {
    const float ev = bex[lane];
    const int ec = bcol[lane];
    int rank = 0;
    for (int j = 0; j < nB; ++j) {
      const float oj = bex[j];
      const int cj = bcol[j];
      if (oj > ev || (oj == ev && cj < ec)) rank++;
    }
    if (rank < slots) {
      const int slot = atomicAdd(&outcnt_s, 1);
      if (slot < KSEL) { outidx[slot] = ec; outval[slot] = fmaxf(ev, 0.0f); }
    }
  }
  // emit H members from regs (value = f16 sim, err << threshold)
#pragma unroll
  for (int r = 0; r < 3; ++r) {
#pragma unroll
    for (int e = 0; e < 8; ++e) {
      const u32 kk = key[r * 8 + e];
      if (kk > hiK) {
        const int i = (r * 256 + t) * 8 + e;
        const int slot = atomicAdd(&outcnt_s, 1);
        if (slot < KSEL) {
          outidx[slot] = (i < segBase ? i : i + SEG_SIZE);
          outval[slot] = fmaxf(keyval(kk), 0.0f);
        }
      }
    }
  }
  __syncthreads();
  if (t < KSEL)
    compact[(size_t)row * KSEL + t] = make_int2(outidx[t], __float_as_int(outval[t]));
}

// ---------------------------------------------------------------------------
// Kernel 4: streaming writer — zero full row, scatter 31 values.
// ---------------------------------------------------------------------------
__global__ __launch_bounds__(256) void write_kernel(
    const int2* __restrict__ compact, float* __restrict__ out) {
  const int row = blockIdx.x;
  const int t = threadIdx.x;
  __shared__ int sidx[KSEL];
  __shared__ float sval[KSEL];
  if (t < KSEL) {
    const int2 e = compact[(size_t)row * KSEL + t];
    sidx[t] = e.x;
    sval[t] = __int_as_float(e.y);
  }
  float* orow = out + (size_t)row * N_NODES;
  const float4 zero4 = make_float4(0.f, 0.f, 0.f, 0.f);
  __syncthreads();
#pragma unroll
  for (int i = 0; i < 8; ++i)
    reinterpret_cast<float4*>(orow)[i * 256 + t] = zero4;
  __syncthreads();
  if (t < KSEL) orow[sidx[t]] = sval[t];
}

// ---------------------------------------------------------------------------
extern "C" void kernel_launch(void* const* d_in, const int* in_sizes, int n_in,
                              void* d_out, int out_size, void* d_ws, size_t ws_size,
                              hipStream_t stream) {
  const float* feat = (const float*)d_in[0];
  const float* w0 = (const float*)d_in[1];
  const float* w1 = (const float*)d_in[2];
  float* out = (float*)d_out;

  u16* embh = (u16*)d_ws;                                           // 8 MB (dead after gemm)
  float* embf = (float*)((char*)d_ws + (size_t)N_NODES * DIM * 2);  // 16 MB
  int2* compact = (int2*)d_ws;                                      // 2 MB, reuses embh region
  __half* simh = (__half*)d_out;                                    // 100 MB packed f16 sims

  prep_kernel<<<N_NODES, 256, 0, stream>>>(feat, w0, w1, embh, embf);
  dim3 grid(48, 64);
  gemm_kernel<<<grid, 256, 0, stream>>>(embh, simh);
  select_kernel<<<N_NODES, 256, 0, stream>>>(simh, embf, compact);
  write_kernel<<<N_NODES, 256, 0, stream>>>(compact, out);
}

// Round 15
// 307.313 us; speedup vs baseline: 1.1357x; 1.1357x over previous
//
#include <hip/hip_runtime.h>
#include <hip/hip_bf16.h>
#include <hip/hip_fp16.h>
#include <math.h>

typedef unsigned short u16;
typedef unsigned int u32;
typedef unsigned long long u64;
typedef __attribute__((ext_vector_type(8))) short bf16x8;
typedef __attribute__((ext_vector_type(4))) float f32x4;

#define N_NODES 8192
#define DIM 512
#define KSEL 31
#define BANDCAP 64
#define CKCAP 64
#define SEG_SIZE 2048
#define NVALID 6144   // cross-segment columns per row
#define BAND_ULP 8    // band half-width in f16 ulps (R14-verified)

// wave-local LDS fence: all prior DS ops done + compiler barrier
#define FENCE() asm volatile("s_waitcnt lgkmcnt(0)" ::: "memory")

__device__ __forceinline__ float ninf() { return __int_as_float(0xff800000); }

// monotone 16-bit key from f16 bits (larger key <=> larger value)
__device__ __forceinline__ u32 f16key(u32 h) {
  return (h & 0x8000u) ? (0xFFFFu & ~h) : (h | 0x8000u);
}
__device__ __forceinline__ u32 packkeys(u32 w) {  // two f16 -> two keys
  return f16key(w & 0xFFFFu) | (f16key(w >> 16) << 16);
}
__device__ __forceinline__ float keyval(u32 k) {
  const u16 raw = (k & 0x8000u) ? (u16)(k ^ 0x8000u) : (u16)(~k & 0xFFFFu);
  __half_raw hr; hr.x = raw;
  return __half2float(__half(hr));
}

#define GLD_LDS16(g, l)                                        \
  __builtin_amdgcn_global_load_lds(                            \
      (const __attribute__((address_space(1))) void*)(g),      \
      (__attribute__((address_space(3))) void*)(l), 16, 0, 0)

// ---------------------------------------------------------------------------
// Kernel 1: emb replicating numpy-f32 bit-exactly (verified R6).
// ---------------------------------------------------------------------------
__global__ __launch_bounds__(256) void prep_kernel(
    const float* __restrict__ feat, const float* __restrict__ w0,
    const float* __restrict__ w1, u16* __restrict__ embh,
    float* __restrict__ embf) {
#pragma clang fp contract(off)
  const int row = blockIdx.x;
  const int t = threadIdx.x;
  __shared__ float hs[DIM];
  __shared__ float partial[32];
  __shared__ float rinv_sh;

  const float2 x = *reinterpret_cast<const float2*>(feat + (size_t)row * DIM + t * 2);
  const float2 a = *reinterpret_cast<const float2*>(w0 + t * 2);
  const float2 b = *reinterpret_cast<const float2*>(w1 + t * 2);
  const float h0 = fmaxf(x.x * a.x, 0.0f) * b.x;
  const float h1 = fmaxf(x.y * a.y, 0.0f) * b.y;
  hs[t * 2] = h0;
  hs[t * 2 + 1] = h1;
  __syncthreads();

  if (t < 32) {
    const int base = (t >> 3) * 128 + (t & 7);
    float v = hs[base];
    float acc = v * v;
    for (int i = 1; i < 16; ++i) {
      v = hs[base + 8 * i];
      const float vv = v * v;
      acc = acc + vv;
    }
    partial[t] = acc;
  }
  __syncthreads();
  if (t == 0) {
    float B[4];
    for (int blk = 0; blk < 4; ++blk) {
      const float* p = &partial[blk * 8];
      B[blk] = ((p[0] + p[1]) + (p[2] + p[3])) + ((p[4] + p[5]) + (p[6] + p[7]));
    }
    const float s = (B[0] + B[1]) + (B[2] + B[3]);
    const float sp = s + 1e-24f;
    const float qf = (float)sqrt((double)sp);
    rinv_sh = (float)(1.0 / (double)qf);
  }
  __syncthreads();
  const float rinv = rinv_sh;
  const float e0 = h0 * rinv;
  const float e1 = h1 * rinv;
  *reinterpret_cast<float2*>(embf + (size_t)row * DIM + t * 2) = make_float2(e0, e1);
  __hip_bfloat162 bb;
  bb.x = __float2bfloat16(e0);
  bb.y = __float2bfloat16(e1);
  *reinterpret_cast<__hip_bfloat162*>(embh + (size_t)row * DIM + t * 2) = bb;
}

// ---------------------------------------------------------------------------
// Kernel 2: ranking sim (bf16 MFMA) -> f16, packed cross-seg columns.
// ---------------------------------------------------------------------------
__global__ __launch_bounds__(256) void gemm_kernel(const u16* __restrict__ embh,
                                                   __half* __restrict__ simh) {
  __shared__ u16 As[128][64];
  __shared__ u16 Bs[128][64];
  const int tid = threadIdx.x;
  const int lane = tid & 63;
  const int wave = tid >> 6;
  const int wm = wave >> 1;
  const int wn = wave & 1;
  const int rowTile = blockIdx.y;
  const int segTileBase = (rowTile >> 4) << 4;
  const int cT = blockIdx.x;
  const int colTile = cT < segTileBase ? cT : cT + 16;
  const int row0 = rowTile * 128;
  const int col0 = colTile * 128;

  f32x4 acc[4][4] = {};

  for (int k0 = 0; k0 < DIM; k0 += 64) {
#pragma unroll
    for (int i = 0; i < 4; ++i) {
      const int flat = i * 256 + tid;
      const int r = flat >> 3;
      const int c = (flat & 7) * 8;
      GLD_LDS16(embh + (size_t)(row0 + r) * DIM + k0 + c, &As[r][c]);
      GLD_LDS16(embh + (size_t)(col0 + r) * DIM + k0 + c, &Bs[r][c]);
    }
    __syncthreads();
#pragma unroll
    for (int kk = 0; kk < 2; ++kk) {
      bf16x8 afr[4], bfr[4];
      const int koff = kk * 32 + (lane >> 4) * 8;
      const int rsel = lane & 15;
#pragma unroll
      for (int m = 0; m < 4; ++m)
        afr[m] = *reinterpret_cast<const bf16x8*>(&As[wm * 64 + m * 16 + rsel][koff]);
#pragma unroll
      for (int n = 0; n < 4; ++n)
        bfr[n] = *reinterpret_cast<const bf16x8*>(&Bs[wn * 64 + n * 16 + rsel][koff]);
#pragma unroll
      for (int m = 0; m < 4; ++m)
#pragma unroll
        for (int n = 0; n < 4; ++n)
          acc[m][n] = __builtin_amdgcn_mfma_f32_16x16x32_bf16(afr[m], bfr[n],
                                                              acc[m][n], 0, 0, 0);
    }
    __syncthreads();
  }
#pragma unroll
  for (int m = 0; m < 4; ++m)
#pragma unroll
    for (int n = 0; n < 4; ++n)
#pragma unroll
      for (int j = 0; j < 4; ++j) {
        const int r = row0 + wm * 64 + m * 16 + (lane >> 4) * 4 + j;
        const int pcol = cT * 128 + wn * 64 + n * 16 + (lane & 15);
        simh[(size_t)r * NVALID + pcol] = __float2half(acc[m][n][j]);
      }
}

// ---------------------------------------------------------------------------
// Kernel 3: WAVE-AUTONOMOUS per-row selection. One wave per row; no
// __syncthreads. Row keys in registers; min/max-scaled 256-bin histogram
// (uniform bins -> no atomic hot spots) + <=3 refinement levels finds the
// exact 31st key; H = {key > k31+8ulp} emits f16 value; band +-8ulp resolved
// by bit-exact np-sequential dots (lanes of same wave). R14 semantics.
// ---------------------------------------------------------------------------
__global__ __launch_bounds__(256) void select_kernel(
    const __half* __restrict__ simh, const float* __restrict__ embf,
    int2* __restrict__ compact) {
  const int lane = threadIdx.x & 63;
  const int wave = threadIdx.x >> 6;
  const int row = blockIdx.x * 4 + wave;

  __shared__ __align__(16) float er[4][DIM];
  __shared__ u32 hist[4][257];
  __shared__ int bcol[4][BANDCAP];
  __shared__ float bex[4][BANDCAP];
  __shared__ u32 ckey[4][CKCAP];
  __shared__ int outidx_s[4][KSEL];
  __shared__ float outval_s[4][KSEL];
  __shared__ int cnts[4][2];  // [0]=scratch counter, [1]=outcnt

  const int segBase = (row >> 11) << 11;

  // --- load row (96 f16/lane) + own emb row into wave LDS region ---
  uint4 q[12];
  {
    const uint4* src = reinterpret_cast<const uint4*>(simh + (size_t)row * NVALID);
#pragma unroll
    for (int j = 0; j < 12; ++j) q[j] = src[j * 64 + lane];
    const float4* ef = reinterpret_cast<const float4*>(embf + (size_t)row * DIM);
    reinterpret_cast<float4*>(&er[wave][lane * 8])[0] = ef[lane * 2];
    reinterpret_cast<float4*>(&er[wave][lane * 8])[1] = ef[lane * 2 + 1];
  }
  if (lane == 0) { cnts[wave][0] = 0; cnts[wave][1] = 0; }

  // --- pack keys: pk[v>>1] holds keys for values v (lo half v&1==0) ---
  u32 pk[48];
#pragma unroll
  for (int j = 0; j < 12; ++j) {
    pk[j * 4 + 0] = packkeys(q[j].x);
    pk[j * 4 + 1] = packkeys(q[j].y);
    pk[j * 4 + 2] = packkeys(q[j].z);
    pk[j * 4 + 3] = packkeys(q[j].w);
  }
#define KEY(v) (((v) & 1) ? (pk[(v) >> 1] >> 16) : (pk[(v) >> 1] & 0xFFFFu))

  // --- wave min/max of keys ---
  u32 kmin = 0xFFFFu, kmax = 0;
#pragma unroll
  for (int v = 0; v < 96; ++v) {
    const u32 k = KEY(v);
    kmin = min(kmin, k);
    kmax = max(kmax, k);
  }
#pragma unroll
  for (int off = 32; off > 0; off >>= 1) {
    kmin = min(kmin, (u32)__shfl_xor((int)kmin, off, 64));
    kmax = max(kmax, (u32)__shfl_xor((int)kmax, off, 64));
  }

  // --- refinement levels: find exact 31st-largest key k31 ---
  u32 lo = kmin, w = kmax - kmin + 1;
  u32 need = KSEL;
  u32 k31 = lo;
  bool done = false;
  for (int lvl = 0; lvl < 4 && !done; ++lvl) {
    if (w == 1) { k31 = lo; break; }
    // zero wave hist
#pragma unroll
    for (int z = 0; z < 4; ++z) hist[wave][lane * 4 + z] = 0;
    FENCE();
    // histogram over uniform bins
#pragma unroll
    for (int v = 0; v < 96; ++v) {
      const u32 k = KEY(v);
      const u32 d = k - lo;
      if (k >= lo && d < w) atomicAdd(&hist[wave][(d << 8) / w], 1u);
    }
    FENCE();
    // suffix counts over 256 bins (each lane owns 4)
    const int x = lane * 4;
    const u32 b0 = hist[wave][x], b1 = hist[wave][x + 1];
    const u32 b2 = hist[wave][x + 2], b3 = hist[wave][x + 3];
    const u32 tot = b0 + b1 + b2 + b3;
    u32 inc = tot;
#pragma unroll
    for (int off = 1; off < 64; off <<= 1) {
      const u32 vv = (u32)__shfl_down((int)inc, off, 64);
      if (lane + off < 64) inc += vv;
    }
    const u32 exc = inc - tot;
    const u32 g3 = exc, g2 = g3 + b3, g1 = g2 + b2, g0 = g1 + b1;
    int sel = -1;
    u32 gsel = 0, csel = 0;
    if (g3 < need && g3 + b3 >= need) { sel = x + 3; gsel = g3; csel = b3; }
    else if (g2 < need && g2 + b2 >= need) { sel = x + 2; gsel = g2; csel = b2; }
    else if (g1 < need && g1 + b1 >= need) { sel = x + 1; gsel = g1; csel = b1; }
    else if (g0 < need && g0 + b0 >= need) { sel = x;     gsel = g0; csel = b0; }
    const u64 bal = __ballot(sel >= 0);
    const int srcl = (int)(__ffsll((unsigned long long)bal) - 1);
    sel  = __shfl(sel, srcl, 64);
    gsel = (u32)__shfl((int)gsel, srcl, 64);
    csel = (u32)__shfl((int)csel, srcl, 64);
    const u32 needIn = need - gsel;  // rank within selected bin
    if (csel <= CKCAP) {
      // collect selected-bin keys, rank exactly
      if (lane == 0) cnts[wave][0] = 0;
      FENCE();
#pragma unroll
      for (int v = 0; v < 96; ++v) {
        const u32 k = KEY(v);
        const u32 d = k - lo;
        if (k >= lo && d < w && (int)((d << 8) / w) == sel) {
          const int slot = atomicAdd(&cnts[wave][0], 1);
          if (slot < CKCAP) ckey[wave][slot] = k;
        }
      }
      FENCE();
      const int cc = min(cnts[wave][0], CKCAP);
      const u32 kv = (lane < cc) ? ckey[wave][lane] : 0;
      int a = 0, e = 0;
      for (int j = 0; j < cc; ++j) {
        const u32 o = ckey[wave][j];
        a += (o > kv) ? 1 : 0;
        e += (o == kv) ? 1 : 0;
      }
      const bool hit = (lane < cc) && ((u32)a < needIn) && (needIn <= (u32)(a + e));
      const u64 hb = __ballot(hit);
      const int hl = (int)(__ffsll((unsigned long long)hb) - 1);
      k31 = (u32)__shfl((int)kv, hl, 64);
      done = true;
    } else {
      // descend into bin sel
      const u32 nlo = lo + ((u32)sel * w + 255u) / 256u;
      const u32 nhi = lo + (((u32)sel + 1u) * w + 255u) / 256u - 1u;
      lo = nlo;
      w = nhi - nlo + 1;
      need = needIn;
      k31 = lo;
    }
  }

  const u32 hiK = k31 + BAND_ULP;
  const u32 loK = (k31 >= BAND_ULP) ? k31 - BAND_ULP : 0;

  // --- classify: count H, collect band cols ---
  if (lane == 0) cnts[wave][0] = 0;
  FENCE();
  int myH = 0;
#pragma unroll
  for (int v = 0; v < 96; ++v) {
    const u32 k = KEY(v);
    if (k > hiK) {
      myH++;
    } else if (k >= loK) {
      const int slot = atomicAdd(&cnts[wave][0], 1);
      if (slot < BANDCAP) {
        const int i = (((v >> 3) * 64 + lane) << 3) + (v & 7);  // packed col
        bcol[wave][slot] = (i < segBase) ? i : i + SEG_SIZE;
      }
    }
  }
#pragma unroll
  for (int off = 32; off > 0; off >>= 1) myH += __shfl_xor(myH, off, 64);
  const int nH = myH;
  const int slots = KSEL - nH;
  FENCE();
  const int nB = min(cnts[wave][0], BANDCAP);

  // --- bit-exact np-sequential dots for band members (verified R6) ---
  if (lane < nB) {
#pragma clang fp contract(off)
    const float4* g4 =
        reinterpret_cast<const float4*>(embf + (size_t)bcol[wave][lane] * DIM);
    const float4* e4 = reinterpret_cast<const float4*>(&er[wave][0]);
    float acc = 0.0f;
    for (int k4 = 0; k4 < DIM / 4; ++k4) {
      const float4 a = e4[k4];
      const float4 b = g4[k4];
      acc = acc + a.x * b.x;
      acc = acc + a.y * b.y;
      acc = acc + a.z * b.z;
      acc = acc + a.w * b.w;
    }
    bex[wave][lane] = acc;
  }
  FENCE();

  // --- band rank (exact desc, col asc), emit winners ---
  if (lane < nB) {
    const float ev = bex[wave][lane];
    const int ec = bcol[wave][lane];
    int r = 0;
    for (int j = 0; j < nB; ++j) {
      const float oj = bex[wave][j];
      const int cj = bcol[wave][j];
      if (oj > ev || (oj == ev && cj < ec)) r++;
    }
    if (r < slots) {
      const int slot = atomicAdd(&cnts[wave][1], 1);
      if (slot < KSEL) { outidx_s[wave][slot] = ec; outval_s[wave][slot] = fmaxf(ev, 0.0f); }
    }
  }
  // --- emit H members (value = f16 sim) ---
#pragma unroll
  for (int v = 0; v < 96; ++v) {
    const u32 k = KEY(v);
    if (k > hiK) {
      const int i = (((v >> 3) * 64 + lane) << 3) + (v & 7);
      const int slot = atomicAdd(&cnts[wave][1], 1);
      if (slot < KSEL) {
        outidx_s[wave][slot] = (i < segBase) ? i : i + SEG_SIZE;
        outval_s[wave][slot] = fmaxf(keyval(k), 0.0f);
      }
    }
  }
  FENCE();
  if (lane < KSEL)
    compact[(size_t)row * KSEL + lane] =
        make_int2(outidx_s[wave][lane], __float_as_int(outval_s[wave][lane]));
#undef KEY
}

// ---------------------------------------------------------------------------
// Kernel 4: streaming writer — zero full row, scatter 31 values.
// ---------------------------------------------------------------------------
__global__ __launch_bounds__(256) void write_kernel(
    const int2* __restrict__ compact, float* __restrict__ out) {
  const int row = blockIdx.x;
  const int t = threadIdx.x;
  __shared__ int sidx[KSEL];
  __shared__ float sval[KSEL];
  if (t < KSEL) {
    const int2 e = compact[(size_t)row * KSEL + t];
    sidx[t] = e.x;
    sval[t] = __int_as_float(e.y);
  }
  float* orow = out + (size_t)row * N_NODES;
  const float4 zero4 = make_float4(0.f, 0.f, 0.f, 0.f);
  __syncthreads();
#pragma unroll
  for (int i = 0; i < 8; ++i)
    reinterpret_cast<float4*>(orow)[i * 256 + t] = zero4;
  __syncthreads();
  if (t < KSEL) orow[sidx[t]] = sval[t];
}

// ---------------------------------------------------------------------------
extern "C" void kernel_launch(void* const* d_in, const int* in_sizes, int n_in,
                              void* d_out, int out_size, void* d_ws, size_t ws_size,
                              hipStream_t stream) {
  const float* feat = (const float*)d_in[0];
  const float* w0 = (const float*)d_in[1];
  const float* w1 = (const float*)d_in[2];
  float* out = (float*)d_out;

  u16* embh = (u16*)d_ws;                                           // 8 MB (dead after gemm)
  float* embf = (float*)((char*)d_ws + (size_t)N_NODES * DIM * 2);  // 16 MB
  int2* compact = (int2*)d_ws;                                      // 2 MB, reuses embh region
  __half* simh = (__half*)d_out;                                    // 100 MB packed f16 sims

  prep_kernel<<<N_NODES, 256, 0, stream>>>(feat, w0, w1, embh, embf);
  dim3 grid(48, 64);
  gemm_kernel<<<grid, 256, 0, stream>>>(embh, simh);
  select_kernel<<<N_NODES / 4, 256, 0, stream>>>(simh, embf, compact);
  write_kernel<<<N_NODES, 256, 0, stream>>>(compact, out);
}

// Round 16
// 292.979 us; speedup vs baseline: 1.1912x; 1.0489x over previous
//
#include <hip/hip_runtime.h>
#include <hip/hip_bf16.h>
#include <hip/hip_fp16.h>
#include <math.h>

typedef unsigned short u16;
typedef unsigned int u32;
typedef unsigned long long u64;
typedef __attribute__((ext_vector_type(8))) short bf16x8;
typedef __attribute__((ext_vector_type(4))) float f32x4;

#define N_NODES 8192
#define DIM 512
#define KSEL 31
#define BANDCAP 64
#define CKCAP 64
#define SEG_SIZE 2048
#define NVALID 6144   // cross-segment columns per row
#define BAND_ULP 8    // band half-width in f16 ulps (R14/R15-verified)

// wave-local LDS fence: all prior DS ops done + compiler barrier
#define FENCE() asm volatile("s_waitcnt lgkmcnt(0)" ::: "memory")

__device__ __forceinline__ float ninf() { return __int_as_float(0xff800000); }

// monotone 16-bit key from f16 bits (larger key <=> larger value)
__device__ __forceinline__ u32 f16key(u32 h) {
  return (h & 0x8000u) ? (0xFFFFu & ~h) : (h | 0x8000u);
}
__device__ __forceinline__ float keyval(u32 k) {
  const u16 raw = (k & 0x8000u) ? (u16)(k ^ 0x8000u) : (u16)(~k & 0xFFFFu);
  __half_raw hr; hr.x = raw;
  return __half2float(__half(hr));
}

#define GLD_LDS16(g, l)                                        \
  __builtin_amdgcn_global_load_lds(                            \
      (const __attribute__((address_space(1))) void*)(g),      \
      (__attribute__((address_space(3))) void*)(l), 16, 0, 0)

// ---------------------------------------------------------------------------
// Kernel 1: emb replicating numpy-f32 bit-exactly (verified R6).
// ---------------------------------------------------------------------------
__global__ __launch_bounds__(256) void prep_kernel(
    const float* __restrict__ feat, const float* __restrict__ w0,
    const float* __restrict__ w1, u16* __restrict__ embh,
    float* __restrict__ embf) {
#pragma clang fp contract(off)
  const int row = blockIdx.x;
  const int t = threadIdx.x;
  __shared__ float hs[DIM];
  __shared__ float partial[32];
  __shared__ float rinv_sh;

  const float2 x = *reinterpret_cast<const float2*>(feat + (size_t)row * DIM + t * 2);
  const float2 a = *reinterpret_cast<const float2*>(w0 + t * 2);
  const float2 b = *reinterpret_cast<const float2*>(w1 + t * 2);
  const float h0 = fmaxf(x.x * a.x, 0.0f) * b.x;
  const float h1 = fmaxf(x.y * a.y, 0.0f) * b.y;
  hs[t * 2] = h0;
  hs[t * 2 + 1] = h1;
  __syncthreads();

  if (t < 32) {
    const int base = (t >> 3) * 128 + (t & 7);
    float v = hs[base];
    float acc = v * v;
    for (int i = 1; i < 16; ++i) {
      v = hs[base + 8 * i];
      const float vv = v * v;
      acc = acc + vv;
    }
    partial[t] = acc;
  }
  __syncthreads();
  if (t == 0) {
    float B[4];
    for (int blk = 0; blk < 4; ++blk) {
      const float* p = &partial[blk * 8];
      B[blk] = ((p[0] + p[1]) + (p[2] + p[3])) + ((p[4] + p[5]) + (p[6] + p[7]));
    }
    const float s = (B[0] + B[1]) + (B[2] + B[3]);
    const float sp = s + 1e-24f;
    const float qf = (float)sqrt((double)sp);
    rinv_sh = (float)(1.0 / (double)qf);
  }
  __syncthreads();
  const float rinv = rinv_sh;
  const float e0 = h0 * rinv;
  const float e1 = h1 * rinv;
  *reinterpret_cast<float2*>(embf + (size_t)row * DIM + t * 2) = make_float2(e0, e1);
  __hip_bfloat162 bb;
  bb.x = __float2bfloat16(e0);
  bb.y = __float2bfloat16(e1);
  *reinterpret_cast<__hip_bfloat162*>(embh + (size_t)row * DIM + t * 2) = bb;
}

// ---------------------------------------------------------------------------
// Kernel 2: ranking sim (bf16 MFMA) -> f16, packed cross-seg columns.
// ---------------------------------------------------------------------------
__global__ __launch_bounds__(256) void gemm_kernel(const u16* __restrict__ embh,
                                                   __half* __restrict__ simh) {
  __shared__ u16 As[128][64];
  __shared__ u16 Bs[128][64];
  const int tid = threadIdx.x;
  const int lane = tid & 63;
  const int wave = tid >> 6;
  const int wm = wave >> 1;
  const int wn = wave & 1;
  const int rowTile = blockIdx.y;
  const int segTileBase = (rowTile >> 4) << 4;
  const int cT = blockIdx.x;
  const int colTile = cT < segTileBase ? cT : cT + 16;
  const int row0 = rowTile * 128;
  const int col0 = colTile * 128;

  f32x4 acc[4][4] = {};

  for (int k0 = 0; k0 < DIM; k0 += 64) {
#pragma unroll
    for (int i = 0; i < 4; ++i) {
      const int flat = i * 256 + tid;
      const int r = flat >> 3;
      const int c = (flat & 7) * 8;
      GLD_LDS16(embh + (size_t)(row0 + r) * DIM + k0 + c, &As[r][c]);
      GLD_LDS16(embh + (size_t)(col0 + r) * DIM + k0 + c, &Bs[r][c]);
    }
    __syncthreads();
#pragma unroll
    for (int kk = 0; kk < 2; ++kk) {
      bf16x8 afr[4], bfr[4];
      const int koff = kk * 32 + (lane >> 4) * 8;
      const int rsel = lane & 15;
#pragma unroll
      for (int m = 0; m < 4; ++m)
        afr[m] = *reinterpret_cast<const bf16x8*>(&As[wm * 64 + m * 16 + rsel][koff]);
#pragma unroll
      for (int n = 0; n < 4; ++n)
        bfr[n] = *reinterpret_cast<const bf16x8*>(&Bs[wn * 64 + n * 16 + rsel][koff]);
#pragma unroll
      for (int m = 0; m < 4; ++m)
#pragma unroll
        for (int n = 0; n < 4; ++n)
          acc[m][n] = __builtin_amdgcn_mfma_f32_16x16x32_bf16(afr[m], bfr[n],
                                                              acc[m][n], 0, 0, 0);
    }
    __syncthreads();
  }
#pragma unroll
  for (int m = 0; m < 4; ++m)
#pragma unroll
    for (int n = 0; n < 4; ++n)
#pragma unroll
      for (int j = 0; j < 4; ++j) {
        const int r = row0 + wm * 64 + m * 16 + (lane >> 4) * 4 + j;
        const int pcol = cT * 128 + wn * 64 + n * 16 + (lane & 15);
        simh[(size_t)r * NVALID + pcol] = __float2half(acc[m][n][j]);
      }
}

// ---------------------------------------------------------------------------
// Kernel 3: WAVE-AUTONOMOUS per-row selection, tail-window histogram.
// One wave per row, no __syncthreads. Keys extracted on the fly from q[12]
// (no pk array -> lower VGPR). Histogram only the [kmax-1023, kmax] window
// with 4-ulp bins (shifts, no division; ~1 atomic/lane); escalate window /
// descend to 1-ulp bins only for pathological rows. Exact k31; H/band
// semantics identical to R14/R15 (BAND_ULP=8, bit-exact np chain in band).
// ---------------------------------------------------------------------------
__global__ __launch_bounds__(256) void select_kernel(
    const __half* __restrict__ simh, const float* __restrict__ embf,
    int2* __restrict__ compact) {
  const int lane = threadIdx.x & 63;
  const int wave = threadIdx.x >> 6;
  const int row = blockIdx.x * 4 + wave;

  __shared__ __align__(16) float er[4][DIM];
  __shared__ u32 hist[4][257];
  __shared__ int bcol[4][BANDCAP];
  __shared__ float bex[4][BANDCAP];
  __shared__ u32 ckey[4][CKCAP];
  __shared__ int outidx_s[4][KSEL];
  __shared__ float outval_s[4][KSEL];
  __shared__ int cnts[4][2];  // [0]=scratch counter, [1]=outcnt

  const int segBase = (row >> 11) << 11;

  // --- load row (96 f16/lane) + own emb row into wave LDS region ---
  uint4 q[12];
  {
    const uint4* src = reinterpret_cast<const uint4*>(simh + (size_t)row * NVALID);
#pragma unroll
    for (int j = 0; j < 12; ++j) q[j] = src[j * 64 + lane];
    const float4* ef = reinterpret_cast<const float4*>(embf + (size_t)row * DIM);
    reinterpret_cast<float4*>(&er[wave][lane * 8])[0] = ef[lane * 2];
    reinterpret_cast<float4*>(&er[wave][lane * 8])[1] = ef[lane * 2 + 1];
  }
  if (lane == 0) { cnts[wave][0] = 0; cnts[wave][1] = 0; }

  // key iterator: body(key, packed_col_index)
  auto forEachKey = [&](auto&& body) {
#pragma unroll
    for (int j = 0; j < 12; ++j) {
      const u32 ws[4] = {q[j].x, q[j].y, q[j].z, q[j].w};
#pragma unroll
      for (int e = 0; e < 8; ++e) {
        const u32 k = f16key((ws[e >> 1] >> (16 * (e & 1))) & 0xFFFFu);
        body(k, ((j * 64 + lane) << 3) + e);
      }
    }
  };

  // --- wave min/max of keys ---
  u32 kmin = 0xFFFFu, kmax = 0;
  forEachKey([&](u32 k, int) {
    kmin = min(kmin, k);
    kmax = max(kmax, k);
  });
#pragma unroll
  for (int off = 32; off > 0; off >>= 1) {
    kmin = min(kmin, (u32)__shfl_xor((int)kmin, off, 64));
    kmax = max(kmax, (u32)__shfl_xor((int)kmax, off, 64));
  }

  // --- find exact 31st-largest key k31 (tail-window histogram) ---
  u32 base = (kmax > 1023u) ? kmax - 1023u : 0u;
  u32 shift = 2;          // 4-ulp bins over 1024-ulp tail window
  int tier = 0;
  u32 need = KSEL;
  u32 k31 = kmin;
  bool done = false;
  for (int guard = 0; guard < 6 && !done; ++guard) {
    // zero wave hist
#pragma unroll
    for (int z = 0; z < 4; ++z) hist[wave][lane * 4 + z] = 0;
    FENCE();
    // histogram (bins are shifts; out-of-window keys skipped)
    forEachKey([&](u32 k, int) {
      if (k >= base) {
        const u32 d = (k - base) >> shift;
        if (d < 256u) atomicAdd(&hist[wave][d], 1u);
      }
    });
    FENCE();
    // suffix counts over 256 bins (each lane owns 4)
    const int x = lane * 4;
    const u32 b0 = hist[wave][x], b1 = hist[wave][x + 1];
    const u32 b2 = hist[wave][x + 2], b3 = hist[wave][x + 3];
    const u32 tot = b0 + b1 + b2 + b3;
    u32 inc = tot;
#pragma unroll
    for (int off = 1; off < 64; off <<= 1) {
      const u32 vv = (u32)__shfl_down((int)inc, off, 64);
      if (lane + off < 64) inc += vv;
    }
    const u32 exc = inc - tot;
    const u32 g3 = exc, g2 = g3 + b3, g1 = g2 + b2, g0 = g1 + b1;
    int sel = -1;
    u32 gsel = 0, csel = 0;
    if (g3 < need && g3 + b3 >= need) { sel = x + 3; gsel = g3; csel = b3; }
    else if (g2 < need && g2 + b2 >= need) { sel = x + 2; gsel = g2; csel = b2; }
    else if (g1 < need && g1 + b1 >= need) { sel = x + 1; gsel = g1; csel = b1; }
    else if (g0 < need && g0 + b0 >= need) { sel = x;     gsel = g0; csel = b0; }
    const u64 bal = __ballot(sel >= 0);
    if (bal == 0) {
      // window too small (cum < need): escalate
      if (tier == 0) { base = (kmax > 16383u) ? kmax - 16383u : 0u; shift = 6; tier = 1; }
      else { base = kmin; shift = 8; tier = 2; }  // full range, guaranteed
      need = KSEL;
      continue;
    }
    const int srcl = (int)(__ffsll((unsigned long long)bal) - 1);
    sel  = __shfl(sel, srcl, 64);
    gsel = (u32)__shfl((int)gsel, srcl, 64);
    csel = (u32)__shfl((int)csel, srcl, 64);
    const u32 needIn = need - gsel;  // rank within selected bin
    if (csel <= CKCAP) {
      // collect selected-bin keys, rank exactly
      if (lane == 0) cnts[wave][0] = 0;
      FENCE();
      forEachKey([&](u32 k, int) {
        if (k >= base && ((k - base) >> shift) == (u32)sel) {
          const int slot = atomicAdd(&cnts[wave][0], 1);
          if (slot < CKCAP) ckey[wave][slot] = k;
        }
      });
      FENCE();
      const int cc = min(cnts[wave][0], CKCAP);
      const u32 kv = (lane < cc) ? ckey[wave][lane] : 0;
      int a = 0, e = 0;
      for (int j = 0; j < cc; ++j) {
        const u32 o = ckey[wave][j];
        a += (o > kv) ? 1 : 0;
        e += (o == kv) ? 1 : 0;
      }
      const bool hit = (lane < cc) && ((u32)a < needIn) && (needIn <= (u32)(a + e));
      const u64 hb = __ballot(hit);
      const int hl = (int)(__ffsll((unsigned long long)hb) - 1);
      k31 = (u32)__shfl((int)kv, hl, 64);
      done = true;
    } else if (shift == 0) {
      k31 = base + (u32)sel;  // 1-ulp bin: all keys equal
      done = true;
    } else {
      // descend into bin sel with 1-ulp bins
      base = base + ((u32)sel << shift);
      shift = 0;
      need = needIn;
    }
  }

  const u32 hiK = k31 + BAND_ULP;
  const u32 loK = (k31 >= BAND_ULP) ? k31 - BAND_ULP : 0;

  // --- classify: count H, collect band cols ---
  if (lane == 0) cnts[wave][0] = 0;
  FENCE();
  int myH = 0;
  forEachKey([&](u32 k, int i) {
    if (k > hiK) {
      myH++;
    } else if (k >= loK) {
      const int slot = atomicAdd(&cnts[wave][0], 1);
      if (slot < BANDCAP) bcol[wave][slot] = (i < segBase) ? i : i + SEG_SIZE;
    }
  });
#pragma unroll
  for (int off = 32; off > 0; off >>= 1) myH += __shfl_xor(myH, off, 64);
  const int nH = myH;
  const int slots = KSEL - nH;
  FENCE();
  const int nB = min(cnts[wave][0], BANDCAP);

  // --- bit-exact np-sequential dots for band members (verified R6) ---
  if (lane < nB) {
#pragma clang fp contract(off)
    const float4* g4 =
        reinterpret_cast<const float4*>(embf + (size_t)bcol[wave][lane] * DIM);
    const float4* e4 = reinterpret_cast<const float4*>(&er[wave][0]);
    float acc = 0.0f;
    for (int k4 = 0; k4 < DIM / 4; ++k4) {
      const float4 a = e4[k4];
      const float4 b = g4[k4];
      acc = acc + a.x * b.x;
      acc = acc + a.y * b.y;
      acc = acc + a.z * b.z;
      acc = acc + a.w * b.w;
    }
    bex[wave][lane] = acc;
  }
  FENCE();

  // --- band rank (exact desc, col asc), emit winners ---
  if (lane < nB) {
    const float ev = bex[wave][lane];
    const int ec = bcol[wave][lane];
    int r = 0;
    for (int j = 0; j < nB; ++j) {
      const float oj = bex[wave][j];
      const int cj = bcol[wave][j];
      if (oj > ev || (oj == ev && cj < ec)) r++;
    }
    if (r < slots) {
      const int slot = atomicAdd(&cnts[wave][1], 1);
      if (slot < KSEL) { outidx_s[wave][slot] = ec; outval_s[wave][slot] = fmaxf(ev, 0.0f); }
    }
  }
  // --- emit H members (value = f16 sim) ---
  forEachKey([&](u32 k, int i) {
    if (k > hiK) {
      const int slot = atomicAdd(&cnts[wave][1], 1);
      if (slot < KSEL) {
        outidx_s[wave][slot] = (i < segBase) ? i : i + SEG_SIZE;
        outval_s[wave][slot] = fmaxf(keyval(k), 0.0f);
      }
    }
  });
  FENCE();
  if (lane < KSEL)
    compact[(size_t)row * KSEL + lane] =
        make_int2(outidx_s[wave][lane], __float_as_int(outval_s[wave][lane]));
}

// ---------------------------------------------------------------------------
// Kernel 4: streaming writer — zero full row, scatter 31 values.
// ---------------------------------------------------------------------------
__global__ __launch_bounds__(256) void write_kernel(
    const int2* __restrict__ compact, float* __restrict__ out) {
  const int row = blockIdx.x;
  const int t = threadIdx.x;
  __shared__ int sidx[KSEL];
  __shared__ float sval[KSEL];
  if (t < KSEL) {
    const int2 e = compact[(size_t)row * KSEL + t];
    sidx[t] = e.x;
    sval[t] = __int_as_float(e.y);
  }
  float* orow = out + (size_t)row * N_NODES;
  const float4 zero4 = make_float4(0.f, 0.f, 0.f, 0.f);
  __syncthreads();
#pragma unroll
  for (int i = 0; i < 8; ++i)
    reinterpret_cast<float4*>(orow)[i * 256 + t] = zero4;
  __syncthreads();
  if (t < KSEL) orow[sidx[t]] = sval[t];
}

// ---------------------------------------------------------------------------
extern "C" void kernel_launch(void* const* d_in, const int* in_sizes, int n_in,
                              void* d_out, int out_size, void* d_ws, size_t ws_size,
                              hipStream_t stream) {
  const float* feat = (const float*)d_in[0];
  const float* w0 = (const float*)d_in[1];
  const float* w1 = (const float*)d_in[2];
  float* out = (float*)d_out;

  u16* embh = (u16*)d_ws;                                           // 8 MB (dead after gemm)
  float* embf = (float*)((char*)d_ws + (size_t)N_NODES * DIM * 2);  // 16 MB
  int2* compact = (int2*)d_ws;                                      // 2 MB, reuses embh region
  __half* simh = (__half*)d_out;                                    // 100 MB packed f16 sims

  prep_kernel<<<N_NODES, 256, 0, stream>>>(feat, w0, w1, embh, embf);
  dim3 grid(48, 64);
  gemm_kernel<<<grid, 256, 0, stream>>>(embh, simh);
  select_kernel<<<N_NODES / 4, 256, 0, stream>>>(simh, embf, compact);
  write_kernel<<<N_NODES, 256, 0, stream>>>(compact, out);
}

// Round 17
// 251.332 us; speedup vs baseline: 1.3886x; 1.1657x over previous
//
#include <hip/hip_runtime.h>
#include <hip/hip_bf16.h>
#include <hip/hip_fp16.h>
#include <math.h>

typedef unsigned short u16;
typedef unsigned int u32;
typedef unsigned long long u64;
typedef __attribute__((ext_vector_type(8))) short bf16x8;
typedef __attribute__((ext_vector_type(4))) float f32x4;

#define N_NODES 8192
#define DIM 512
#define KSEL 31
#define BANDCAP 128
#define SEG_SIZE 2048
#define NVALID 6144   // cross-segment columns per row
#define BAND_ULP 8    // band half-width in f16 ulps (R14/R15/R16-verified)

// wave-local LDS fence: all prior DS ops done + compiler barrier
#define FENCE() asm volatile("s_waitcnt lgkmcnt(0)" ::: "memory")

// monotone 16-bit key from f16 bits (larger key <=> larger value)
__device__ __forceinline__ u32 f16key(u32 h) {
  return (h & 0x8000u) ? (0xFFFFu & ~h) : (h | 0x8000u);
}
__device__ __forceinline__ float keyval(u32 k) {
  const u16 raw = (k & 0x8000u) ? (u16)(k ^ 0x8000u) : (u16)(~k & 0xFFFFu);
  __half_raw hr; hr.x = raw;
  return __half2float(__half(hr));
}

#define GLD_LDS16(g, l)                                        \
  __builtin_amdgcn_global_load_lds(                            \
      (const __attribute__((address_space(1))) void*)(g),      \
      (__attribute__((address_space(3))) void*)(l), 16, 0, 0)

// ---------------------------------------------------------------------------
// Kernel 1: emb replicating numpy-f32 bit-exactly (verified R6). Also zeroes
// the per-row kmax accumulator used by the gemm epilogue.
// ---------------------------------------------------------------------------
__global__ __launch_bounds__(256) void prep_kernel(
    const float* __restrict__ feat, const float* __restrict__ w0,
    const float* __restrict__ w1, u16* __restrict__ embh,
    float* __restrict__ embf, u32* __restrict__ kmax32) {
#pragma clang fp contract(off)
  const int row = blockIdx.x;
  const int t = threadIdx.x;
  __shared__ float hs[DIM];
  __shared__ float partial[32];
  __shared__ float rinv_sh;

  const float2 x = *reinterpret_cast<const float2*>(feat + (size_t)row * DIM + t * 2);
  const float2 a = *reinterpret_cast<const float2*>(w0 + t * 2);
  const float2 b = *reinterpret_cast<const float2*>(w1 + t * 2);
  const float h0 = fmaxf(x.x * a.x, 0.0f) * b.x;
  const float h1 = fmaxf(x.y * a.y, 0.0f) * b.y;
  hs[t * 2] = h0;
  hs[t * 2 + 1] = h1;
  if (t == 0) kmax32[row] = 0u;
  __syncthreads();

  if (t < 32) {
    const int base = (t >> 3) * 128 + (t & 7);
    float v = hs[base];
    float acc = v * v;
    for (int i = 1; i < 16; ++i) {
      v = hs[base + 8 * i];
      const float vv = v * v;
      acc = acc + vv;
    }
    partial[t] = acc;
  }
  __syncthreads();
  if (t == 0) {
    float B[4];
    for (int blk = 0; blk < 4; ++blk) {
      const float* p = &partial[blk * 8];
      B[blk] = ((p[0] + p[1]) + (p[2] + p[3])) + ((p[4] + p[5]) + (p[6] + p[7]));
    }
    const float s = (B[0] + B[1]) + (B[2] + B[3]);
    const float sp = s + 1e-24f;
    const float qf = (float)sqrt((double)sp);
    rinv_sh = (float)(1.0 / (double)qf);
  }
  __syncthreads();
  const float rinv = rinv_sh;
  const float e0 = h0 * rinv;
  const float e1 = h1 * rinv;
  *reinterpret_cast<float2*>(embf + (size_t)row * DIM + t * 2) = make_float2(e0, e1);
  __hip_bfloat162 bb;
  bb.x = __float2bfloat16(e0);
  bb.y = __float2bfloat16(e1);
  *reinterpret_cast<__hip_bfloat162*>(embh + (size_t)row * DIM + t * 2) = bb;
}

// ---------------------------------------------------------------------------
// Kernel 2: ranking sim (bf16 MFMA) -> f16, packed cross-seg columns.
// Epilogue also accumulates per-row max (monotone f32-key atomicMax).
// ---------------------------------------------------------------------------
__global__ __launch_bounds__(256) void gemm_kernel(const u16* __restrict__ embh,
                                                   __half* __restrict__ simh,
                                                   u32* __restrict__ kmax32) {
  __shared__ u16 As[128][64];
  __shared__ u16 Bs[128][64];
  const int tid = threadIdx.x;
  const int lane = tid & 63;
  const int wave = tid >> 6;
  const int wm = wave >> 1;
  const int wn = wave & 1;
  const int rowTile = blockIdx.y;
  const int segTileBase = (rowTile >> 4) << 4;
  const int cT = blockIdx.x;
  const int colTile = cT < segTileBase ? cT : cT + 16;
  const int row0 = rowTile * 128;
  const int col0 = colTile * 128;

  f32x4 acc[4][4] = {};

  for (int k0 = 0; k0 < DIM; k0 += 64) {
#pragma unroll
    for (int i = 0; i < 4; ++i) {
      const int flat = i * 256 + tid;
      const int r = flat >> 3;
      const int c = (flat & 7) * 8;
      GLD_LDS16(embh + (size_t)(row0 + r) * DIM + k0 + c, &As[r][c]);
      GLD_LDS16(embh + (size_t)(col0 + r) * DIM + k0 + c, &Bs[r][c]);
    }
    __syncthreads();
#pragma unroll
    for (int kk = 0; kk < 2; ++kk) {
      bf16x8 afr[4], bfr[4];
      const int koff = kk * 32 + (lane >> 4) * 8;
      const int rsel = lane & 15;
#pragma unroll
      for (int m = 0; m < 4; ++m)
        afr[m] = *reinterpret_cast<const bf16x8*>(&As[wm * 64 + m * 16 + rsel][koff]);
#pragma unroll
      for (int n = 0; n < 4; ++n)
        bfr[n] = *reinterpret_cast<const bf16x8*>(&Bs[wn * 64 + n * 16 + rsel][koff]);
#pragma unroll
      for (int m = 0; m < 4; ++m)
#pragma unroll
        for (int n = 0; n < 4; ++n)
          acc[m][n] = __builtin_amdgcn_mfma_f32_16x16x32_bf16(afr[m], bfr[n],
                                                              acc[m][n], 0, 0, 0);
    }
    __syncthreads();
  }
#pragma unroll
  for (int m = 0; m < 4; ++m)
#pragma unroll
    for (int n = 0; n < 4; ++n)
#pragma unroll
      for (int j = 0; j < 4; ++j) {
        const int r = row0 + wm * 64 + m * 16 + (lane >> 4) * 4 + j;
        const int pcol = cT * 128 + wn * 64 + n * 16 + (lane & 15);
        simh[(size_t)r * NVALID + pcol] = __float2half(acc[m][n][j]);
      }
  // per-row max over this tile -> global atomicMax (monotone f32 key)
#pragma unroll
  for (int m = 0; m < 4; ++m) {
#pragma unroll
    for (int j = 0; j < 4; ++j) {
      float vmax = fmaxf(fmaxf(acc[m][0][j], acc[m][1][j]),
                         fmaxf(acc[m][2][j], acc[m][3][j]));
#pragma unroll
      for (int off = 1; off < 16; off <<= 1)
        vmax = fmaxf(vmax, __shfl_xor(vmax, off, 64));
      if ((lane & 15) == 0) {
        const int r = row0 + wm * 64 + m * 16 + (lane >> 4) * 4 + j;
        const u32 b = __float_as_uint(vmax);
        const u32 kk = (b & 0x80000000u) ? ~b : (b | 0x80000000u);
        atomicMax(&kmax32[r], kk);
      }
    }
  }
}

// ---------------------------------------------------------------------------
// Kernel 3: wave-autonomous select, stateless streaming (2 scans, no row
// state in registers). Scan 1: 4-ulp-bin histogram of the [kmax-511,kmax]
// tail (escalate window if needed; 1-ulp descent for wide bins) -> interval
// [binlo,binhi] containing the 31st key. Scan 2: H = {k > binhi+8} emits f16
// value; band [binlo-8,binhi+8] collected and resolved by bit-exact
// np-sequential dots (verified R6). Sandwich: E<=4 ulps => exact membership.
// ---------------------------------------------------------------------------
__global__ __launch_bounds__(256, 6) void select_kernel(
    const __half* __restrict__ simh, const float* __restrict__ embf,
    const u32* __restrict__ kmax32, int2* __restrict__ compact) {
  const int lane = threadIdx.x & 63;
  const int wave = threadIdx.x >> 6;
  const int row = blockIdx.x * 4 + wave;

  __shared__ __align__(16) float er[4][DIM];
  __shared__ u32 hist[4][257];
  __shared__ int bcol[4][BANDCAP];
  __shared__ float bex[4][BANDCAP];
  __shared__ int outidx_s[4][KSEL];
  __shared__ float outval_s[4][KSEL];
  __shared__ int cnts[4][2];  // [0]=band count, [1]=out count

  const int segBase = (row >> 11) << 11;
  const uint4* src = reinterpret_cast<const uint4*>(simh + (size_t)row * NVALID);

  // stage own emb row; init
  {
    const float4* ef = reinterpret_cast<const float4*>(embf + (size_t)row * DIM);
    reinterpret_cast<float4*>(&er[wave][lane * 8])[0] = ef[lane * 2];
    reinterpret_cast<float4*>(&er[wave][lane * 8])[1] = ef[lane * 2 + 1];
  }
  if (lane == 0) { cnts[wave][0] = 0; cnts[wave][1] = 0; }
  if (lane < KSEL) { outidx_s[wave][lane] = segBase; outval_s[wave][lane] = 0.0f; }

  // row-max f16 key from gemm's f32-key accumulator (RTN monotone)
  u32 kmax16;
  {
    const u32 kk = kmax32[row];
    const u32 fb = (kk & 0x80000000u) ? (kk ^ 0x80000000u) : ~kk;
    const __half h = __float2half(__uint_as_float(fb));
    kmax16 = f16key((u32)__half_as_ushort(h));
  }

  // scan-1 loop: locate interval [binlo, binhi] containing the 31st key
  u32 base = (kmax16 > 511u) ? kmax16 - 511u : 0u;
  u32 winTop = kmax16;
  u32 shift = 2;
  u32 need = KSEL;
  int tier = 0;
  u32 binlo = 0, binhi = 0;
  for (int guard = 0; guard < 6; ++guard) {
#pragma unroll
    for (int z = 0; z < 4; ++z) hist[wave][lane * 4 + z] = 0;
    FENCE();
    for (int j = 0; j < 12; ++j) {
      const uint4 v = src[j * 64 + lane];
      const u32 ws[4] = {v.x, v.y, v.z, v.w};
#pragma unroll
      for (int e = 0; e < 8; ++e) {
        const u32 k = f16key((ws[e >> 1] >> (16 * (e & 1))) & 0xFFFFu);
        if (k >= base && k <= winTop)
          atomicAdd(&hist[wave][(k - base) >> shift], 1u);
      }
    }
    FENCE();
    const int x = lane * 4;
    const u32 b0 = hist[wave][x], b1 = hist[wave][x + 1];
    const u32 b2 = hist[wave][x + 2], b3 = hist[wave][x + 3];
    const u32 tot = b0 + b1 + b2 + b3;
    u32 inc = tot;
#pragma unroll
    for (int off = 1; off < 64; off <<= 1) {
      const u32 vv = (u32)__shfl_down((int)inc, off, 64);
      if (lane + off < 64) inc += vv;
    }
    const u32 exc = inc - tot;
    const u32 g3 = exc, g2 = g3 + b3, g1 = g2 + b2, g0 = g1 + b1;
    int sel = -1;
    u32 gsel = 0;
    if (g3 < need && g3 + b3 >= need) { sel = x + 3; gsel = g3; }
    else if (g2 < need && g2 + b2 >= need) { sel = x + 2; gsel = g2; }
    else if (g1 < need && g1 + b1 >= need) { sel = x + 1; gsel = g1; }
    else if (g0 < need && g0 + b0 >= need) { sel = x;     gsel = g0; }
    const u64 bal = __ballot(sel >= 0);
    if (bal == 0) {  // window held < need keys: escalate
      if (tier == 0) { base = (kmax16 > 8191u) ? kmax16 - 8191u : 0u; shift = 5; }
      else { base = 0u; shift = 8; }
      winTop = kmax16; need = KSEL; tier++;
      continue;
    }
    const int srcl = (int)(__ffsll((unsigned long long)bal) - 1);
    sel  = __shfl(sel, srcl, 64);
    gsel = (u32)__shfl((int)gsel, srcl, 64);
    binlo = base + ((u32)sel << shift);
    binhi = min(binlo + (1u << shift) - 1u, winTop);
    if (shift > 2) {  // wide bin: descend to 1-ulp bins for a tight interval
      base = binlo; winTop = binhi; shift = 0; need = need - gsel;
      continue;
    }
    break;
  }

  const u32 hiK = binhi + BAND_ULP;
  const u32 loK = (binlo >= BAND_ULP) ? binlo - BAND_ULP : 0u;

  // scan 2 (L2-hot): emit H directly (f16 value), collect band cols
  for (int j = 0; j < 12; ++j) {
    const uint4 v = src[j * 64 + lane];
    const u32 ws[4] = {v.x, v.y, v.z, v.w};
#pragma unroll
    for (int e = 0; e < 8; ++e) {
      const u32 k = f16key((ws[e >> 1] >> (16 * (e & 1))) & 0xFFFFu);
      if (k > hiK) {
        const int slot = atomicAdd(&cnts[wave][1], 1);
        const int i = ((j * 64 + lane) << 3) + e;
        if (slot < KSEL) {
          outidx_s[wave][slot] = (i < segBase) ? i : i + SEG_SIZE;
          outval_s[wave][slot] = fmaxf(keyval(k), 0.0f);
        }
      } else if (k >= loK) {
        const int slot = atomicAdd(&cnts[wave][0], 1);
        const int i = ((j * 64 + lane) << 3) + e;
        if (slot < BANDCAP) bcol[wave][slot] = (i < segBase) ? i : i + SEG_SIZE;
      }
    }
  }
  FENCE();
  const int nH = min(cnts[wave][1], KSEL);
  const int slots = KSEL - nH;
  const int nB = min(cnts[wave][0], BANDCAP);

  // bit-exact np-sequential dots for band members (verified R6 rounding)
  if (lane < nB) {
#pragma clang fp contract(off)
    const float4* g4 =
        reinterpret_cast<const float4*>(embf + (size_t)bcol[wave][lane] * DIM);
    const float4* e4 = reinterpret_cast<const float4*>(&er[wave][0]);
    float acc = 0.0f;
    for (int k4 = 0; k4 < DIM / 4; ++k4) {
      const float4 a = e4[k4];
      const float4 b = g4[k4];
      acc = acc + a.x * b.x;
      acc = acc + a.y * b.y;
      acc = acc + a.z * b.z;
      acc = acc + a.w * b.w;
    }
    bex[wave][lane] = acc;
  }
  FENCE();

  // band rank (exact desc, col asc); winners fill remaining slots
  if (lane < nB) {
    const float ev = bex[wave][lane];
    const int ec = bcol[wave][lane];
    int r = 0;
    for (int j = 0; j < nB; ++j) {
      const float oj = bex[wave][j];
      const int cj = bcol[wave][j];
      if (oj > ev || (oj == ev && cj < ec)) r++;
    }
    if (r < slots) {
      const int slot = atomicAdd(&cnts[wave][1], 1);
      if (slot < KSEL) { outidx_s[wave][slot] = ec; outval_s[wave][slot] = fmaxf(ev, 0.0f); }
    }
  }
  FENCE();
  if (lane < KSEL)
    compact[(size_t)row * KSEL + lane] =
        make_int2(outidx_s[wave][lane], __float_as_int(outval_s[wave][lane]));
}

// ---------------------------------------------------------------------------
// Kernel 4: streaming writer — zero full row, scatter 31 values.
// ---------------------------------------------------------------------------
__global__ __launch_bounds__(256) void write_kernel(
    const int2* __restrict__ compact, float* __restrict__ out) {
  const int row = blockIdx.x;
  const int t = threadIdx.x;
  __shared__ int sidx[KSEL];
  __shared__ float sval[KSEL];
  if (t < KSEL) {
    const int2 e = compact[(size_t)row * KSEL + t];
    sidx[t] = e.x;
    sval[t] = __int_as_float(e.y);
  }
  float* orow = out + (size_t)row * N_NODES;
  const float4 zero4 = make_float4(0.f, 0.f, 0.f, 0.f);
  __syncthreads();
#pragma unroll
  for (int i = 0; i < 8; ++i)
    reinterpret_cast<float4*>(orow)[i * 256 + t] = zero4;
  __syncthreads();
  if (t < KSEL) orow[sidx[t]] = sval[t];
}

// ---------------------------------------------------------------------------
extern "C" void kernel_launch(void* const* d_in, const int* in_sizes, int n_in,
                              void* d_out, int out_size, void* d_ws, size_t ws_size,
                              hipStream_t stream) {
  const float* feat = (const float*)d_in[0];
  const float* w0 = (const float*)d_in[1];
  const float* w1 = (const float*)d_in[2];
  float* out = (float*)d_out;

  u16* embh = (u16*)d_ws;                                           // [0,8MB) dead after gemm
  float* embf = (float*)((char*)d_ws + (size_t)N_NODES * DIM * 2);  // [8,24MB)
  u32* kmax32 = (u32*)((char*)d_ws + (size_t)24 * 1024 * 1024);     // 32 KB
  int2* compact = (int2*)d_ws;                                      // 2 MB, reuses embh
  __half* simh = (__half*)d_out;                                    // 100 MB packed f16 sims

  prep_kernel<<<N_NODES, 256, 0, stream>>>(feat, w0, w1, embh, embf, kmax32);
  dim3 grid(48, 64);
  gemm_kernel<<<grid, 256, 0, stream>>>(embh, simh, kmax32);
  select_kernel<<<N_NODES / 4, 256, 0, stream>>>(simh, embf, kmax32, compact);
  write_kernel<<<N_NODES, 256, 0, stream>>>(compact, out);
}

// Round 18
// 246.282 us; speedup vs baseline: 1.4171x; 1.0205x over previous
//
#include <hip/hip_runtime.h>
#include <hip/hip_bf16.h>
#include <hip/hip_fp16.h>
#include <math.h>

typedef unsigned short u16;
typedef unsigned int u32;
typedef unsigned long long u64;
typedef __attribute__((ext_vector_type(8))) short bf16x8;
typedef __attribute__((ext_vector_type(4))) float f32x4;

#define N_NODES 8192
#define DIM 512
#define KSEL 31
#define BANDCAP 128
#define SEG_SIZE 2048
#define NVALID 6144   // cross-segment columns per row
#define BAND_ULP 8    // band half-width in f16 ulps (R14..R17-verified)

// monotone 16-bit key from f16 bits (larger key <=> larger value)
__device__ __forceinline__ u32 f16key(u32 h) {
  return (h & 0x8000u) ? (0xFFFFu & ~h) : (h | 0x8000u);
}
__device__ __forceinline__ u32 packkeys(u32 w) {  // two f16 -> two keys
  return f16key(w & 0xFFFFu) | (f16key(w >> 16) << 16);
}
__device__ __forceinline__ float keyval(u32 k) {
  const u16 raw = (k & 0x8000u) ? (u16)(k ^ 0x8000u) : (u16)(~k & 0xFFFFu);
  __half_raw hr; hr.x = raw;
  return __half2float(__half(hr));
}

#define GLD_LDS16(g, l)                                        \
  __builtin_amdgcn_global_load_lds(                            \
      (const __attribute__((address_space(1))) void*)(g),      \
      (__attribute__((address_space(3))) void*)(l), 16, 0, 0)

// ---------------------------------------------------------------------------
// Kernel 1: emb replicating numpy-f32 bit-exactly (verified R6). Also zeroes
// the per-row kmax accumulator used by the gemm epilogue.
// ---------------------------------------------------------------------------
__global__ __launch_bounds__(256) void prep_kernel(
    const float* __restrict__ feat, const float* __restrict__ w0,
    const float* __restrict__ w1, u16* __restrict__ embh,
    float* __restrict__ embf, u32* __restrict__ kmax32) {
#pragma clang fp contract(off)
  const int row = blockIdx.x;
  const int t = threadIdx.x;
  __shared__ float hs[DIM];
  __shared__ float partial[32];
  __shared__ float rinv_sh;

  const float2 x = *reinterpret_cast<const float2*>(feat + (size_t)row * DIM + t * 2);
  const float2 a = *reinterpret_cast<const float2*>(w0 + t * 2);
  const float2 b = *reinterpret_cast<const float2*>(w1 + t * 2);
  const float h0 = fmaxf(x.x * a.x, 0.0f) * b.x;
  const float h1 = fmaxf(x.y * a.y, 0.0f) * b.y;
  hs[t * 2] = h0;
  hs[t * 2 + 1] = h1;
  if (t == 0) kmax32[row] = 0u;
  __syncthreads();

  if (t < 32) {
    const int base = (t >> 3) * 128 + (t & 7);
    float v = hs[base];
    float acc = v * v;
    for (int i = 1; i < 16; ++i) {
      v = hs[base + 8 * i];
      const float vv = v * v;
      acc = acc + vv;
    }
    partial[t] = acc;
  }
  __syncthreads();
  if (t == 0) {
    float B[4];
    for (int blk = 0; blk < 4; ++blk) {
      const float* p = &partial[blk * 8];
      B[blk] = ((p[0] + p[1]) + (p[2] + p[3])) + ((p[4] + p[5]) + (p[6] + p[7]));
    }
    const float s = (B[0] + B[1]) + (B[2] + B[3]);
    const float sp = s + 1e-24f;
    const float qf = (float)sqrt((double)sp);
    rinv_sh = (float)(1.0 / (double)qf);
  }
  __syncthreads();
  const float rinv = rinv_sh;
  const float e0 = h0 * rinv;
  const float e1 = h1 * rinv;
  *reinterpret_cast<float2*>(embf + (size_t)row * DIM + t * 2) = make_float2(e0, e1);
  __hip_bfloat162 bb;
  bb.x = __float2bfloat16(e0);
  bb.y = __float2bfloat16(e1);
  *reinterpret_cast<__hip_bfloat162*>(embh + (size_t)row * DIM + t * 2) = bb;
}

// ---------------------------------------------------------------------------
// Kernel 2: ranking sim (bf16 MFMA) -> f16, packed cross-seg columns.
// Epilogue accumulates per-row max (monotone f32-key atomicMax).
// ---------------------------------------------------------------------------
__global__ __launch_bounds__(256) void gemm_kernel(const u16* __restrict__ embh,
                                                   __half* __restrict__ simh,
                                                   u32* __restrict__ kmax32) {
  __shared__ u16 As[128][64];
  __shared__ u16 Bs[128][64];
  const int tid = threadIdx.x;
  const int lane = tid & 63;
  const int wave = tid >> 6;
  const int wm = wave >> 1;
  const int wn = wave & 1;
  const int rowTile = blockIdx.y;
  const int segTileBase = (rowTile >> 4) << 4;
  const int cT = blockIdx.x;
  const int colTile = cT < segTileBase ? cT : cT + 16;
  const int row0 = rowTile * 128;
  const int col0 = colTile * 128;

  f32x4 acc[4][4] = {};

  for (int k0 = 0; k0 < DIM; k0 += 64) {
#pragma unroll
    for (int i = 0; i < 4; ++i) {
      const int flat = i * 256 + tid;
      const int r = flat >> 3;
      const int c = (flat & 7) * 8;
      GLD_LDS16(embh + (size_t)(row0 + r) * DIM + k0 + c, &As[r][c]);
      GLD_LDS16(embh + (size_t)(col0 + r) * DIM + k0 + c, &Bs[r][c]);
    }
    __syncthreads();
#pragma unroll
    for (int kk = 0; kk < 2; ++kk) {
      bf16x8 afr[4], bfr[4];
      const int koff = kk * 32 + (lane >> 4) * 8;
      const int rsel = lane & 15;
#pragma unroll
      for (int m = 0; m < 4; ++m)
        afr[m] = *reinterpret_cast<const bf16x8*>(&As[wm * 64 + m * 16 + rsel][koff]);
#pragma unroll
      for (int n = 0; n < 4; ++n)
        bfr[n] = *reinterpret_cast<const bf16x8*>(&Bs[wn * 64 + n * 16 + rsel][koff]);
#pragma unroll
      for (int m = 0; m < 4; ++m)
#pragma unroll
        for (int n = 0; n < 4; ++n)
          acc[m][n] = __builtin_amdgcn_mfma_f32_16x16x32_bf16(afr[m], bfr[n],
                                                              acc[m][n], 0, 0, 0);
    }
    __syncthreads();
  }
#pragma unroll
  for (int m = 0; m < 4; ++m)
#pragma unroll
    for (int n = 0; n < 4; ++n)
#pragma unroll
      for (int j = 0; j < 4; ++j) {
        const int r = row0 + wm * 64 + m * 16 + (lane >> 4) * 4 + j;
        const int pcol = cT * 128 + wn * 64 + n * 16 + (lane & 15);
        simh[(size_t)r * NVALID + pcol] = __float2half(acc[m][n][j]);
      }
  // per-row max over this tile -> global atomicMax (monotone f32 key)
#pragma unroll
  for (int m = 0; m < 4; ++m) {
#pragma unroll
    for (int j = 0; j < 4; ++j) {
      float vmax = fmaxf(fmaxf(acc[m][0][j], acc[m][1][j]),
                         fmaxf(acc[m][2][j], acc[m][3][j]));
#pragma unroll
      for (int off = 1; off < 16; off <<= 1)
        vmax = fmaxf(vmax, __shfl_xor(vmax, off, 64));
      if ((lane & 15) == 0) {
        const int r = row0 + wm * 64 + m * 16 + (lane >> 4) * 4 + j;
        const u32 b = __float_as_uint(vmax);
        const u32 kk = (b & 0x80000000u) ? ~b : (b | 0x80000000u);
        atomicMax(&kmax32[r], kk);
      }
    }
  }
}

// ---------------------------------------------------------------------------
// Kernel 3: block-per-row select, register-resident keys, tail-window
// interval sandwich (R17 semantics). 24 keys/thread packed in 12 VGPRs;
// single shared hist; ~4 barriers/row; er read from global (L3-resident).
// H = {k > binhi+8} emits f16 value; band [binlo-8,binhi+8] resolved by
// bit-exact np-sequential dots (verified R6).
// ---------------------------------------------------------------------------
__global__ __launch_bounds__(256) void select_kernel(
    const __half* __restrict__ simh, const float* __restrict__ embf,
    const u32* __restrict__ kmax32, int2* __restrict__ compact) {
  const int row = blockIdx.x;
  const int t = threadIdx.x;
  const int lane = t & 63;
  const int wave = t >> 6;

  __shared__ u32 hist[257];
  __shared__ int bcol[BANDCAP];
  __shared__ float bex[BANDCAP];
  __shared__ int outidx_s[KSEL];
  __shared__ float outval_s[KSEL];
  __shared__ int cnts[2];          // [0]=band count, [1]=out count
  __shared__ u32 sh_lo, sh_hi, sh_need;
  __shared__ int sh_state;         // 0=escalate, 1=descend, 2=done

  const int segBase = (row >> 11) << 11;

  // load row once: 3 uint4/thread, pack keys in place (12 VGPRs total)
  u32 pk[12];
  {
    const uint4* src = reinterpret_cast<const uint4*>(simh + (size_t)row * NVALID);
    const uint4 a = src[t], b = src[256 + t], c = src[512 + t];
    pk[0] = packkeys(a.x); pk[1] = packkeys(a.y);
    pk[2] = packkeys(a.z); pk[3] = packkeys(a.w);
    pk[4] = packkeys(b.x); pk[5] = packkeys(b.y);
    pk[6] = packkeys(b.z); pk[7] = packkeys(b.w);
    pk[8] = packkeys(c.x); pk[9] = packkeys(c.y);
    pk[10] = packkeys(c.z); pk[11] = packkeys(c.w);
  }
#define KEY(v) ((pk[(v) >> 1] >> (((v) & 1) * 16)) & 0xFFFFu)
  // column of value v (v = word*2+half; word w of uint4 j maps to col bits)
#define COL(v) ((((((v) >> 3) * 256) + t) << 3) + ((v) & 7))

  if (t < KSEL) { outidx_s[t] = segBase; outval_s[t] = 0.0f; }
  if (t == 0) { cnts[0] = 0; cnts[1] = 0; }

  // row-max f16 key from gemm's f32-key accumulator (RTN monotone)
  u32 kmax16;
  {
    const u32 kk = kmax32[row];
    const u32 fb = (kk & 0x80000000u) ? (kk ^ 0x80000000u) : ~kk;
    const __half h = __float2half(__uint_as_float(fb));
    kmax16 = f16key((u32)__half_as_ushort(h));
  }

  // locate interval [binlo, binhi] containing the 31st-largest key
  u32 base = (kmax16 > 511u) ? kmax16 - 511u : 0u;
  u32 winTop = kmax16;
  u32 shift = 2;
  u32 need = KSEL;
  int tier = 0;
  for (int guard = 0; guard < 6; ++guard) {
    hist[t] = 0;
    if (t == 0) hist[256] = 0;
    __syncthreads();
#pragma unroll
    for (int v = 0; v < 24; ++v) {
      const u32 k = KEY(v);
      if (k >= base && k <= winTop) atomicAdd(&hist[(k - base) >> shift], 1u);
    }
    __syncthreads();
    if (wave == 0) {
      const int x = lane * 4;
      const u32 b0 = hist[x], b1 = hist[x + 1];
      const u32 b2 = hist[x + 2], b3 = hist[x + 3];
      const u32 tot = b0 + b1 + b2 + b3;
      u32 inc = tot;
#pragma unroll
      for (int off = 1; off < 64; off <<= 1) {
        const u32 vv = (u32)__shfl_down((int)inc, off, 64);
        if (lane + off < 64) inc += vv;
      }
      const u32 exc = inc - tot;
      const u32 g3 = exc, g2 = g3 + b3, g1 = g2 + b2, g0 = g1 + b1;
      int sel = -1;
      u32 gsel = 0;
      if (g3 < need && g3 + b3 >= need) { sel = x + 3; gsel = g3; }
      else if (g2 < need && g2 + b2 >= need) { sel = x + 2; gsel = g2; }
      else if (g1 < need && g1 + b1 >= need) { sel = x + 1; gsel = g1; }
      else if (g0 < need && g0 + b0 >= need) { sel = x;     gsel = g0; }
      const u64 bal = __ballot(sel >= 0);
      if (lane == 0 && bal == 0) sh_state = 0;  // escalate
      if (bal != 0) {
        const int srcl = (int)(__ffsll((unsigned long long)bal) - 1);
        sel  = __shfl(sel, srcl, 64);
        gsel = (u32)__shfl((int)gsel, srcl, 64);
        if (lane == 0) {
          const u32 blo = base + ((u32)sel << shift);
          const u32 bhi = min(blo + (1u << shift) - 1u, winTop);
          sh_lo = blo; sh_hi = bhi; sh_need = need - gsel;
          sh_state = (shift > 2) ? 1 : 2;
        }
      }
    }
    __syncthreads();
    const int st = sh_state;
    if (st == 2) break;
    if (st == 1) {  // descend into wide bin with 1-ulp bins
      base = sh_lo; winTop = sh_hi; shift = 0; need = sh_need;
    } else {        // escalate window
      ++tier;
      if (tier == 1) { base = (kmax16 > 8191u) ? kmax16 - 8191u : 0u; shift = 5; }
      else { base = 0u; shift = 8; }
      winTop = kmax16; need = KSEL;
    }
    __syncthreads();
  }
  const u32 binlo = sh_lo, binhi = sh_hi;
  const u32 hiK = binhi + BAND_ULP;
  const u32 loK = (binlo >= BAND_ULP) ? binlo - BAND_ULP : 0u;

  // classify from regs: emit H (f16 value), collect band cols
#pragma unroll
  for (int v = 0; v < 24; ++v) {
    const u32 k = KEY(v);
    if (k > hiK) {
      const int slot = atomicAdd(&cnts[1], 1);
      const int i = COL(v);
      if (slot < KSEL) {
        outidx_s[slot] = (i < segBase) ? i : i + SEG_SIZE;
        outval_s[slot] = fmaxf(keyval(k), 0.0f);
      }
    } else if (k >= loK) {
      const int slot = atomicAdd(&cnts[0], 1);
      const int i = COL(v);
      if (slot < BANDCAP) bcol[slot] = (i < segBase) ? i : i + SEG_SIZE;
    }
  }
  __syncthreads();
  const int nH = min(cnts[1], KSEL);
  const int slots = KSEL - nH;
  const int nB = min(cnts[0], BANDCAP);

  // bit-exact np-sequential dots for band members (verified R6 rounding);
  // er read from global (same addresses across threads -> cache broadcast)
  if (t < nB) {
#pragma clang fp contract(off)
    const float4* g4 =
        reinterpret_cast<const float4*>(embf + (size_t)bcol[t] * DIM);
    const float4* e4 = reinterpret_cast<const float4*>(embf + (size_t)row * DIM);
    float acc = 0.0f;
    for (int k4 = 0; k4 < DIM / 4; ++k4) {
      const float4 a = e4[k4];
      const float4 b = g4[k4];
      acc = acc + a.x * b.x;
      acc = acc + a.y * b.y;
      acc = acc + a.z * b.z;
      acc = acc + a.w * b.w;
    }
    bex[t] = acc;
  }
  __syncthreads();

  // band rank (exact desc, col asc); winners fill remaining slots
  if (t < nB) {
    const float ev = bex[t];
    const int ec = bcol[t];
    int r = 0;
    for (int j = 0; j < nB; ++j) {
      const float oj = bex[j];
      const int cj = bcol[j];
      if (oj > ev || (oj == ev && cj < ec)) r++;
    }
    if (r < slots) {
      const int slot = atomicAdd(&cnts[1], 1);
      if (slot < KSEL) { outidx_s[slot] = ec; outval_s[slot] = fmaxf(ev, 0.0f); }
    }
  }
  __syncthreads();
  if (t < KSEL)
    compact[(size_t)row * KSEL + t] =
        make_int2(outidx_s[t], __float_as_int(outval_s[t]));
#undef KEY
#undef COL
}

// ---------------------------------------------------------------------------
// Kernel 4: streaming writer — zero full row, scatter 31 values.
// ---------------------------------------------------------------------------
__global__ __launch_bounds__(256) void write_kernel(
    const int2* __restrict__ compact, float* __restrict__ out) {
  const int row = blockIdx.x;
  const int t = threadIdx.x;
  __shared__ int sidx[KSEL];
  __shared__ float sval[KSEL];
  if (t < KSEL) {
    const int2 e = compact[(size_t)row * KSEL + t];
    sidx[t] = e.x;
    sval[t] = __int_as_float(e.y);
  }
  float* orow = out + (size_t)row * N_NODES;
  const float4 zero4 = make_float4(0.f, 0.f, 0.f, 0.f);
  __syncthreads();
#pragma unroll
  for (int i = 0; i < 8; ++i)
    reinterpret_cast<float4*>(orow)[i * 256 + t] = zero4;
  __syncthreads();
  if (t < KSEL) orow[sidx[t]] = sval[t];
}

// ---------------------------------------------------------------------------
extern "C" void kernel_launch(void* const* d_in, const int* in_sizes, int n_in,
                              void* d_out, int out_size, void* d_ws, size_t ws_size,
                              hipStream_t stream) {
  const float* feat = (const float*)d_in[0];
  const float* w0 = (const float*)d_in[1];
  const float* w1 = (const float*)d_in[2];
  float* out = (float*)d_out;

  u16* embh = (u16*)d_ws;                                           // [0,8MB) dead after gemm
  float* embf = (float*)((char*)d_ws + (size_t)N_NODES * DIM * 2);  // [8,24MB)
  u32* kmax32 = (u32*)((char*)d_ws + (size_t)24 * 1024 * 1024);     // 32 KB
  int2* compact = (int2*)d_ws;                                      // 2 MB, reuses embh
  __half* simh = (__half*)d_out;                                    // 100 MB packed f16 sims

  prep_kernel<<<N_NODES, 256, 0, stream>>>(feat, w0, w1, embh, embf, kmax32);
  dim3 grid(48, 64);
  gemm_kernel<<<grid, 256, 0, stream>>>(embh, simh, kmax32);
  select_kernel<<<N_NODES, 256, 0, stream>>>(simh, embf, kmax32, compact);
  write_kernel<<<N_NODES, 256, 0, stream>>>(compact, out);
}